// Round 1
// baseline (1689.568 us; speedup 1.0000x reference)
//
#include <hip/hip_runtime.h>
#include <stdint.h>

#define K_DIM 4096
#define N_DIM 11008
#define M_DIM 8192
#define BM 128
#define BN 128
#define BK 32
#define NSLAB (K_DIM / BK)    // 128

// fallback kernel params
#define ASTRIDE 32            // lds_a row stride in halves (fallback)
#define BSTRIDE 40            // lds_b row stride in halves (fallback)

typedef _Float16 half8  __attribute__((ext_vector_type(8)));
typedef _Float16 half2v __attribute__((ext_vector_type(2)));
typedef float    floatx4 __attribute__((ext_vector_type(4)));

#define WS_A_BYTES ((size_t)M_DIM * K_DIM * 2)            // 67,108,864
#define WS_B_BYTES ((size_t)N_DIM * K_DIM * 2)            // 90,177,536
#define WS_NEEDED  (WS_A_BYTES + WS_B_BYTES)              // 157,286,400

__device__ __forceinline__ void async_lds16(const void* g, void* l) {
    __builtin_amdgcn_global_load_lds(
        (const __attribute__((address_space(1))) uint32_t*)g,
        (__attribute__((address_space(3))) uint32_t*)l, 16, 0, 0);
}

// ---------------- prepass 1: x fp32 -> fp16 (lossless, values are fp16-representable) ----
__global__ __launch_bounds__(256) void cvt_a(const float* __restrict__ x,
                                             _Float16* __restrict__ xh) {
    const size_t i = ((size_t)blockIdx.x * 256 + threadIdx.x) * 8;
    const float4 a = *(const float4*)(x + i);
    const float4 b = *(const float4*)(x + i + 4);
    half8 h;
    h[0] = (_Float16)a.x; h[1] = (_Float16)a.y; h[2] = (_Float16)a.z; h[3] = (_Float16)a.w;
    h[4] = (_Float16)b.x; h[5] = (_Float16)b.y; h[6] = (_Float16)b.z; h[7] = (_Float16)b.w;
    *(half8*)(xh + i) = h;
}

// ---------------- prepass 2: packed 2-bit ternary + scales -> fp16 W[n][k] --------------
// Exact {-s, 0, +s} via the v_perm byte-template trick (same numerics as the
// in-loop dequant that previously validated at absmax 0.125).
__global__ __launch_bounds__(256) void dequant_b(const int* __restrict__ pw,
                                                 const float* __restrict__ scales,
                                                 _Float16* __restrict__ wh) {
    const int n   = blockIdx.x * 64 + (threadIdx.x & 63);
    const int kpo = threadIdx.x >> 6;              // 0..3
    const int kpb = blockIdx.y * 64;               // kp quarter base
    #pragma unroll 4
    for (int i = 0; i < 16; ++i) {
        const int kp = kpb + i * 4 + kpo;          // packed-dword row (16 k's)
        const uint32_t v = (uint32_t)pw[(size_t)kp * N_DIM + n];
        const _Float16 sh = (_Float16)scales[(size_t)(kp >> 3) * N_DIM + n];  // lossless
        const uint32_t sbits = (uint32_t)__builtin_bit_cast(unsigned short, sh);
        // template bytes: [0]=lo(s) [1]=hi(+s) [2]=0x00 [3]=hi(-s); s > 0
        const uint32_t tmpl = sbits | (((sbits >> 8) ^ 0x80u) << 24);
        uint32_t q[8];
        #pragma unroll
        for (int j = 0; j < 8; ++j) {
            uint32_t t4 = (v >> (4 * j)) & 0xFu;             // c0 @bits1:0, c1 @bits3:2
            uint32_t sp = (t4 | (t4 << 14)) & 0x00030003u;   // c0 @byte0, c1 @byte2
            uint32_t sel = ((sp & 0x00010001u) << 1) | ((0x00030003u - sp) << 8);
            q[j] = __builtin_amdgcn_perm(tmpl, tmpl, sel);
        }
        _Float16* dst = wh + (size_t)n * K_DIM + kp * 16;
        *(uint4*)(dst)     = make_uint4(q[0], q[1], q[2], q[3]);
        *(uint4*)(dst + 8) = make_uint4(q[4], q[5], q[6], q[7]);
    }
}

// ---------------- main GEMM: fp16 x fp16 (m97 structure, global_load_lds staging) --------
__global__ __launch_bounds__(256, 2) void ternary_gemm_ws(
    const _Float16* __restrict__ xh,   // (M, K) fp16
    const _Float16* __restrict__ wh,   // (N, K) fp16 (dequantized)
    const float*    __restrict__ bias, // (N,) fp32 holding fp16 values
    float*          __restrict__ out)  // (M, N) fp32
{
    __shared__ __align__(16) _Float16 lds_a[BM * BK];   // [m][k] linear (DMA dest)
    __shared__ __align__(16) _Float16 lds_b[BN * BK];   // [n][k] linear (DMA dest)

    const int tid  = threadIdx.x;
    const int lane = tid & 63;
    const int wave = tid >> 6;

    const int n0 = blockIdx.x * BN;
    const int m0 = blockIdx.y * BM;
    const int wm = (wave & 1) * 64;
    const int wn = (wave >> 1) * 64;

    // staging map: thread t -> LDS bytes [t*16, t*16+16) == row t/4, halves (t%4)*8
    const int srow = tid >> 2;        // 0..63 (round 1 adds 64)
    const int skq  = (tid & 3) * 8;   // k offset in halves

    const _Float16* ga0 = xh + (size_t)(m0 + srow) * K_DIM + skq;
    const _Float16* ga1 = ga0 + (size_t)64 * K_DIM;
    const _Float16* gb0 = wh + (size_t)(n0 + srow) * K_DIM + skq;
    const _Float16* gb1 = gb0 + (size_t)64 * K_DIM;
    _Float16* la0 = lds_a + tid * 8;
    _Float16* la1 = lds_a + 2048 + tid * 8;   // +4096 B
    _Float16* lb0 = lds_b + tid * 8;
    _Float16* lb1 = lds_b + 2048 + tid * 8;

    floatx4 acc[4][4];
    #pragma unroll
    for (int i = 0; i < 4; ++i)
        #pragma unroll
        for (int j = 0; j < 4; ++j)
            acc[i][j] = floatx4{0.f, 0.f, 0.f, 0.f};

    const int lr = lane & 15;           // row (A) / col (B,C) within 16-tile
    const int qk = (lane >> 4) * 8;     // k offset of this quad's fragment

    for (int slab = 0; slab < NSLAB; ++slab) {
        const int k0 = slab * BK;

        async_lds16(ga0 + k0, la0);
        async_lds16(ga1 + k0, la1);
        async_lds16(gb0 + k0, lb0);
        async_lds16(gb1 + k0, lb1);

        __syncthreads();   // drains vmcnt(0): DMA'd tile visible to all waves

        half8 af[4], bfr[4];
        #pragma unroll
        for (int t = 0; t < 4; ++t) {
            af[t]  = *(const half8*)&lds_a[(wm + t * 16 + lr) * BK + qk];
            bfr[t] = *(const half8*)&lds_b[(wn + t * 16 + lr) * BK + qk];
        }
        #pragma unroll
        for (int mt = 0; mt < 4; ++mt)
            #pragma unroll
            for (int nt = 0; nt < 4; ++nt)
                acc[mt][nt] = __builtin_amdgcn_mfma_f32_16x16x32_f16(
                    af[mt], bfr[nt], acc[mt][nt], 0, 0, 0);

        __syncthreads();   // protect LDS before next slab's DMA overwrites
    }

    // epilogue: fp32 acc + fp32 bias, stored unrounded (same as validated baseline)
    float bv[4];
    #pragma unroll
    for (int nt = 0; nt < 4; ++nt) bv[nt] = bias[n0 + wn + nt * 16 + lr];

    const int rbase = (lane >> 4) * 4;  // C layout: row = (lane>>4)*4 + reg
    #pragma unroll
    for (int mt = 0; mt < 4; ++mt) {
        #pragma unroll
        for (int nt = 0; nt < 4; ++nt) {
            const int col = n0 + wn + nt * 16 + lr;
            float* op = out + (size_t)(m0 + wm + mt * 16 + rbase) * N_DIM + col;
            floatx4 a = acc[mt][nt];
            #pragma unroll
            for (int r = 0; r < 4; ++r)
                op[(size_t)r * N_DIM] = a[r] + bv[nt];
        }
    }
}

// ---------------- fallback: previous validated kernel (used if ws too small) ------------
__global__ __launch_bounds__(256, 2) void ternary_gemm(
    const float* __restrict__ x,
    const int*   __restrict__ pw,
    const float* __restrict__ scales,
    const float* __restrict__ bias,
    float*       __restrict__ out)
{
    __shared__ __align__(16) _Float16 lds_a[BM * ASTRIDE];
    __shared__ __align__(16) _Float16 lds_b[BN * BSTRIDE];

    const int tid  = threadIdx.x;
    const int lane = tid & 63;
    const int wave = tid >> 6;

    const int n0 = blockIdx.x * BN;
    const int m0 = blockIdx.y * BM;

    const int wm = (wave & 1) * 64;
    const int wn = (wave >> 1) * 64;

    const int nb  = tid & 127;
    const int kpi = tid >> 7;
    const int*   pwp = pw + (size_t)kpi * N_DIM + n0 + nb;
    const float* scp = scales + n0 + nb;
    _Float16* bl = lds_b + nb * BSTRIDE + kpi * 16;

    floatx4 acc[4][4];
    #pragma unroll
    for (int i = 0; i < 4; ++i)
        #pragma unroll
        for (int j = 0; j < 4; ++j)
            acc[i][j] = floatx4{0.f, 0.f, 0.f, 0.f};

    const int lr = lane & 15;
    const int qk = (lane >> 4) * 8;

    for (int slab = 0; slab < NSLAB; ++slab) {
        const int k0 = slab * BK;

        #pragma unroll
        for (int i = 0; i < 4; ++i) {
            const int idx = tid + i * 256;
            const int row = idx >> 3;
            const int kq  = (idx & 7) * 4;
            float4 v4 = *(const float4*)(x + (size_t)(m0 + row) * K_DIM + k0 + kq);
            half2v h0; h0[0] = (_Float16)v4.x; h0[1] = (_Float16)v4.y;
            half2v h1; h1[0] = (_Float16)v4.z; h1[1] = (_Float16)v4.w;
            *(uint2*)(lds_a + row * ASTRIDE + kq) =
                make_uint2(__builtin_bit_cast(uint32_t, h0),
                           __builtin_bit_cast(uint32_t, h1));
        }

        uint32_t v  = (uint32_t)pwp[(size_t)slab * 2 * N_DIM];
        _Float16 sh = (_Float16)scp[(size_t)(slab >> 2) * N_DIM];
        uint32_t sbits = (uint32_t)__builtin_bit_cast(unsigned short, sh);
        uint32_t tmpl = sbits | (((sbits >> 8) ^ 0x80u) << 24);

        uint32_t q[8];
        #pragma unroll
        for (int j = 0; j < 8; ++j) {
            uint32_t t4 = (v >> (4 * j)) & 0xFu;
            uint32_t sp = (t4 | (t4 << 14)) & 0x00030003u;
            uint32_t sel = ((sp & 0x00010001u) << 1) | ((0x00030003u - sp) << 8);
            q[j] = __builtin_amdgcn_perm(tmpl, tmpl, sel);
        }
        *(uint4*)(bl)     = make_uint4(q[0], q[1], q[2], q[3]);
        *(uint4*)(bl + 8) = make_uint4(q[4], q[5], q[6], q[7]);

        __syncthreads();

        half8 af[4], bfr[4];
        #pragma unroll
        for (int t = 0; t < 4; ++t) {
            af[t]  = *(const half8*)&lds_a[(wm + t * 16 + lr) * ASTRIDE + qk];
            bfr[t] = *(const half8*)&lds_b[(wn + t * 16 + lr) * BSTRIDE + qk];
        }
        #pragma unroll
        for (int mt = 0; mt < 4; ++mt)
            #pragma unroll
            for (int nt = 0; nt < 4; ++nt)
                acc[mt][nt] = __builtin_amdgcn_mfma_f32_16x16x32_f16(
                    af[mt], bfr[nt], acc[mt][nt], 0, 0, 0);

        __syncthreads();
    }

    float bv[4];
    #pragma unroll
    for (int nt = 0; nt < 4; ++nt) bv[nt] = bias[n0 + wn + nt * 16 + lr];

    const int rbase = (lane >> 4) * 4;
    #pragma unroll
    for (int mt = 0; mt < 4; ++mt) {
        #pragma unroll
        for (int nt = 0; nt < 4; ++nt) {
            const int col = n0 + wn + nt * 16 + lr;
            float* op = out + (size_t)(m0 + wm + mt * 16 + rbase) * N_DIM + col;
            floatx4 a = acc[mt][nt];
            #pragma unroll
            for (int r = 0; r < 4; ++r)
                op[(size_t)r * N_DIM] = a[r] + bv[nt];
        }
    }
}

extern "C" void kernel_launch(void* const* d_in, const int* in_sizes, int n_in,
                              void* d_out, int out_size, void* d_ws, size_t ws_size,
                              hipStream_t stream) {
    const float* x  = (const float*)d_in[0];
    const int*   pw = (const int*)d_in[1];
    const float* sc = (const float*)d_in[2];
    const float* bs = (const float*)d_in[3];
    float* out = (float*)d_out;

    if (d_ws != nullptr && ws_size >= WS_NEEDED) {
        _Float16* xh = (_Float16*)d_ws;
        _Float16* wh = (_Float16*)((char*)d_ws + WS_A_BYTES);
        // prepass: lossless fp32->fp16 of x, and one-time exact dequant of W
        cvt_a<<<dim3((unsigned)((size_t)M_DIM * K_DIM / (256 * 8))), 256, 0, stream>>>(x, xh);
        dequant_b<<<dim3(N_DIM / 64, 4), 256, 0, stream>>>(pw, sc, wh);
        ternary_gemm_ws<<<dim3(N_DIM / BN, M_DIM / BM), 256, 0, stream>>>(xh, wh, bs, out);
    } else {
        ternary_gemm<<<dim3(N_DIM / BN, M_DIM / BM), 256, 0, stream>>>(x, pw, sc, bs, out);
    }
}

// Round 2
// 1128.381 us; speedup vs baseline: 1.4973x; 1.4973x over previous
//
#include <hip/hip_runtime.h>
#include <stdint.h>

#define K_DIM 4096
#define N_DIM 11008
#define M_DIM 8192
#define BM 256
#define BN 128
#define BK 64
#define NSLAB (K_DIM / BK)    // 64
#define BSTRIDE 72            // lds_b row stride in halves (144 B: bank-rotating pad)

// fallback (round-0 validated) kernel params
#define FBM 128
#define FBK 32
#define FASTRIDE 32
#define FBSTRIDE 40

typedef _Float16 half8  __attribute__((ext_vector_type(8)));
typedef _Float16 half2v __attribute__((ext_vector_type(2)));
typedef float    floatx4 __attribute__((ext_vector_type(4)));

#define WS_NEEDED ((size_t)M_DIM * K_DIM * 2)   // 67,108,864: fp16 copy of x

__device__ __forceinline__ void async_lds16(const void* g, void* l) {
    __builtin_amdgcn_global_load_lds(
        (const __attribute__((address_space(1))) uint32_t*)g,
        (__attribute__((address_space(3))) uint32_t*)l, 16, 0, 0);
}

// ---------------- prepass: x fp32 -> fp16 (lossless; values are fp16-representable) ----
__global__ __launch_bounds__(256) void cvt_a(const float* __restrict__ x,
                                             _Float16* __restrict__ xh) {
    const size_t i = ((size_t)blockIdx.x * 256 + threadIdx.x) * 8;
    const float4 a = *(const float4*)(x + i);
    const float4 b = *(const float4*)(x + i + 4);
    half8 h;
    h[0] = (_Float16)a.x; h[1] = (_Float16)a.y; h[2] = (_Float16)a.z; h[3] = (_Float16)a.w;
    h[4] = (_Float16)b.x; h[5] = (_Float16)b.y; h[6] = (_Float16)b.z; h[7] = (_Float16)b.w;
    *(half8*)(xh + i) = h;
}

// ---------------- main GEMM: A fp16 via global_load_lds (XOR-swizzled), B packed
// dequanted in-loop (validated v_perm path, exact {-s,0,+s}) -----------------------------
__global__ __launch_bounds__(512, 4) void ternary_gemm_hy(
    const _Float16* __restrict__ xh,   // (M, K) fp16
    const int*   __restrict__ pw,      // (K/16, N) packed 2-bit codes
    const float* __restrict__ scales,  // (K/128, N) fp32 holding fp16 values
    const float* __restrict__ bias,    // (N,) fp32 holding fp16 values
    float*       __restrict__ out)     // (M, N) fp32
{
    __shared__ __align__(16) _Float16 lds_a[BM * BK];       // [m][k] linear bytes, XOR-swizzled content
    __shared__ __align__(16) _Float16 lds_b[BN * BSTRIDE];  // [n][k], padded stride

    const int tid  = threadIdx.x;
    const int lane = tid & 63;
    const int wave = tid >> 6;

    const int n0 = blockIdx.x * BN;
    const int m0 = blockIdx.y * BM;
    const int wm = (wave & 3) * 64;    // 8 waves = 4m x 2n
    const int wn = (wave >> 2) * 64;

    // ---- A staging map (4 DMA issues/thread/slab): idx = tid + i*512 ----
    // row = idx>>3 (0..255), chunk c = idx&7; LDS dest byte = idx*16 (linear).
    // Source is PRE-SWIZZLED: global chunk = c ^ (row&7), so the swizzled read
    // below recovers the right data (both-sides-or-neither, rule 21).
    const _Float16* ga[4];
    _Float16* la[4];
    #pragma unroll
    for (int i = 0; i < 4; ++i) {
        const int idx = tid + i * 512;
        const int row = idx >> 3;
        const int c   = idx & 7;
        ga[i] = xh + (size_t)(m0 + row) * K_DIM + ((c ^ (row & 7)) * 8);
        la[i] = lds_a + idx * 8;
    }

    // ---- B staging: one packed dword (16 codes) per thread per slab ----
    const int nb = tid >> 2;            // n within tile, 0..127
    const int kp = tid & 3;             // packed-dword index within slab
    const int*   pwp = pw + (size_t)kp * N_DIM + n0 + nb;
    const float* scp = scales + n0 + nb;
    _Float16* bl = lds_b + nb * BSTRIDE + kp * 16;

    floatx4 acc[4][4];
    #pragma unroll
    for (int i = 0; i < 4; ++i)
        #pragma unroll
        for (int j = 0; j < 4; ++j)
            acc[i][j] = floatx4{0.f, 0.f, 0.f, 0.f};

    const int lr = lane & 15;           // row (A) / col (B,C) within 16-tile
    const int g  = lane >> 4;           // k-quad
    const int qk = g * 8;               // k offset (halves) of this quad's fragment
    const int r7 = lr & 7;

    // hoisted fragment base addresses (halves)
    int abase[4], bbase[4];
    #pragma unroll
    for (int t = 0; t < 4; ++t) {
        abase[t] = (wm + t * 16 + lr) * BK;            // + swizzled chunk later
        bbase[t] = (wn + t * 16 + lr) * BSTRIDE + qk;  // + h*32 later
    }

    for (int slab = 0; slab < NSLAB; ++slab) {
        const int k0 = slab * BK;

        // A: async DMA global->LDS, 4 x 16B per thread
        #pragma unroll
        for (int i = 0; i < 4; ++i)
            async_lds16(ga[i] + k0, la[i]);

        // B: unpack 16 ternary codes -> fp16 {-s, 0, +s} (exact)
        uint32_t v  = (uint32_t)pwp[(size_t)slab * 4 * N_DIM];
        _Float16 sh = (_Float16)scp[(size_t)(slab >> 1) * N_DIM];  // lossless
        uint32_t sbits = (uint32_t)__builtin_bit_cast(unsigned short, sh);
        // template bytes: [0]=lo(s) [1]=hi(+s) [2]=0x00 [3]=hi(-s); s > 0
        uint32_t tmpl = sbits | (((sbits >> 8) ^ 0x80u) << 24);

        uint32_t q[8];
        #pragma unroll
        for (int j = 0; j < 8; ++j) {
            uint32_t t4 = (v >> (4 * j)) & 0xFu;             // c0 @bits1:0, c1 @bits3:2
            uint32_t sp = (t4 | (t4 << 14)) & 0x00030003u;   // c0 @byte0, c1 @byte2
            uint32_t sel = ((sp & 0x00010001u) << 1) | ((0x00030003u - sp) << 8);
            q[j] = __builtin_amdgcn_perm(tmpl, tmpl, sel);
        }
        *(uint4*)(bl)     = make_uint4(q[0], q[1], q[2], q[3]);
        *(uint4*)(bl + 8) = make_uint4(q[4], q[5], q[6], q[7]);

        __syncthreads();   // drains vmcnt(0) (A DMA) + lgkm (B writes)

        #pragma unroll
        for (int h = 0; h < 2; ++h) {
            half8 af[4], bfr[4];
            #pragma unroll
            for (int t = 0; t < 4; ++t) {
                af[t]  = *(const half8*)&lds_a[abase[t] + (((h * 4 + g) ^ r7) * 8)];
                bfr[t] = *(const half8*)&lds_b[bbase[t] + h * 32];
            }
            #pragma unroll
            for (int mt = 0; mt < 4; ++mt)
                #pragma unroll
                for (int nt = 0; nt < 4; ++nt)
                    acc[mt][nt] = __builtin_amdgcn_mfma_f32_16x16x32_f16(
                        af[mt], bfr[nt], acc[mt][nt], 0, 0, 0);
        }

        __syncthreads();   // protect LDS before next slab overwrites
    }

    // ---- epilogue: fp32 acc + fp32 bias, stored unrounded (validated numerics) ----
    float bv[4];
    #pragma unroll
    for (int nt = 0; nt < 4; ++nt) bv[nt] = bias[n0 + wn + nt * 16 + lr];

    const int rbase = g * 4;            // C layout: row = (lane>>4)*4 + reg
    #pragma unroll
    for (int mt = 0; mt < 4; ++mt) {
        #pragma unroll
        for (int nt = 0; nt < 4; ++nt) {
            const int col = n0 + wn + nt * 16 + lr;
            float* op = out + (size_t)(m0 + wm + mt * 16 + rbase) * N_DIM + col;
            floatx4 a = acc[mt][nt];
            #pragma unroll
            for (int r = 0; r < 4; ++r)
                op[(size_t)r * N_DIM] = a[r] + bv[nt];
        }
    }
}

// ---------------- fallback: round-0 validated kernel (used if ws too small) ------------
__global__ __launch_bounds__(256, 2) void ternary_gemm(
    const float* __restrict__ x,
    const int*   __restrict__ pw,
    const float* __restrict__ scales,
    const float* __restrict__ bias,
    float*       __restrict__ out)
{
    __shared__ __align__(16) _Float16 lds_a[FBM * FASTRIDE];
    __shared__ __align__(16) _Float16 lds_b[FBM * FBSTRIDE];

    const int tid  = threadIdx.x;
    const int lane = tid & 63;
    const int wave = tid >> 6;

    const int n0 = blockIdx.x * FBM;
    const int m0 = blockIdx.y * FBM;

    const int wm = (wave & 1) * 64;
    const int wn = (wave >> 1) * 64;

    const int nb  = tid & 127;
    const int kpi = tid >> 7;
    const int*   pwp = pw + (size_t)kpi * N_DIM + n0 + nb;
    const float* scp = scales + n0 + nb;
    _Float16* bl = lds_b + nb * FBSTRIDE + kpi * 16;

    floatx4 acc[4][4];
    #pragma unroll
    for (int i = 0; i < 4; ++i)
        #pragma unroll
        for (int j = 0; j < 4; ++j)
            acc[i][j] = floatx4{0.f, 0.f, 0.f, 0.f};

    const int lr = lane & 15;
    const int qk = (lane >> 4) * 8;

    for (int slab = 0; slab < K_DIM / FBK; ++slab) {
        const int k0 = slab * FBK;

        #pragma unroll
        for (int i = 0; i < 4; ++i) {
            const int idx = tid + i * 256;
            const int row = idx >> 3;
            const int kq  = (idx & 7) * 4;
            float4 v4 = *(const float4*)(x + (size_t)(m0 + row) * K_DIM + k0 + kq);
            half2v h0; h0[0] = (_Float16)v4.x; h0[1] = (_Float16)v4.y;
            half2v h1; h1[0] = (_Float16)v4.z; h1[1] = (_Float16)v4.w;
            *(uint2*)(lds_a + row * FASTRIDE + kq) =
                make_uint2(__builtin_bit_cast(uint32_t, h0),
                           __builtin_bit_cast(uint32_t, h1));
        }

        uint32_t v  = (uint32_t)pwp[(size_t)slab * 2 * N_DIM];
        _Float16 sh = (_Float16)scp[(size_t)(slab >> 2) * N_DIM];
        uint32_t sbits = (uint32_t)__builtin_bit_cast(unsigned short, sh);
        uint32_t tmpl = sbits | (((sbits >> 8) ^ 0x80u) << 24);

        uint32_t q[8];
        #pragma unroll
        for (int j = 0; j < 8; ++j) {
            uint32_t t4 = (v >> (4 * j)) & 0xFu;
            uint32_t sp = (t4 | (t4 << 14)) & 0x00030003u;
            uint32_t sel = ((sp & 0x00010001u) << 1) | ((0x00030003u - sp) << 8);
            q[j] = __builtin_amdgcn_perm(tmpl, tmpl, sel);
        }
        *(uint4*)(bl)     = make_uint4(q[0], q[1], q[2], q[3]);
        *(uint4*)(bl + 8) = make_uint4(q[4], q[5], q[6], q[7]);

        __syncthreads();

        half8 af[4], bfr[4];
        #pragma unroll
        for (int t = 0; t < 4; ++t) {
            af[t]  = *(const half8*)&lds_a[(wm + t * 16 + lr) * FASTRIDE + qk];
            bfr[t] = *(const half8*)&lds_b[(wn + t * 16 + lr) * FBSTRIDE + qk];
        }
        #pragma unroll
        for (int mt = 0; mt < 4; ++mt)
            #pragma unroll
            for (int nt = 0; nt < 4; ++nt)
                acc[mt][nt] = __builtin_amdgcn_mfma_f32_16x16x32_f16(
                    af[mt], bfr[nt], acc[mt][nt], 0, 0, 0);

        __syncthreads();
    }

    float bv[4];
    #pragma unroll
    for (int nt = 0; nt < 4; ++nt) bv[nt] = bias[n0 + wn + nt * 16 + lr];

    const int rbase = (lane >> 4) * 4;
    #pragma unroll
    for (int mt = 0; mt < 4; ++mt) {
        #pragma unroll
        for (int nt = 0; nt < 4; ++nt) {
            const int col = n0 + wn + nt * 16 + lr;
            float* op = out + (size_t)(m0 + wm + mt * 16 + rbase) * N_DIM + col;
            floatx4 a = acc[mt][nt];
            #pragma unroll
            for (int r = 0; r < 4; ++r)
                op[(size_t)r * N_DIM] = a[r] + bv[nt];
        }
    }
}

extern "C" void kernel_launch(void* const* d_in, const int* in_sizes, int n_in,
                              void* d_out, int out_size, void* d_ws, size_t ws_size,
                              hipStream_t stream) {
    const float* x  = (const float*)d_in[0];
    const int*   pw = (const int*)d_in[1];
    const float* sc = (const float*)d_in[2];
    const float* bs = (const float*)d_in[3];
    float* out = (float*)d_out;

    if (d_ws != nullptr && ws_size >= WS_NEEDED) {
        _Float16* xh = (_Float16*)d_ws;
        cvt_a<<<dim3((unsigned)((size_t)M_DIM * K_DIM / (256 * 8))), 256, 0, stream>>>(x, xh);
        ternary_gemm_hy<<<dim3(N_DIM / BN, M_DIM / BM), 512, 0, stream>>>(xh, pw, sc, bs, out);
    } else {
        ternary_gemm<<<dim3(N_DIM / FBM, M_DIM / FBM), 256, 0, stream>>>(x, pw, sc, bs, out);
    }
}